// Round 9
// baseline (616.198 us; speedup 1.0000x reference)
//
#include <hip/hip_runtime.h>
#include <math.h>

#define B_DIM 512
#define K_DIM 2048
#define N_DIM 4096
#define BRN 16
#define NUM_TARGET 4096

#define THR_MIN 0.5
#define THR_MAX 2.0
#define REFRACT 2.0f
#define LN_EPS 1e-5

// ===== GEMM (f64 exact, VALU): dend = X[B,K] @ W[N,K]^T + b =================
// 64x64 tile, BK=32, 256 threads, 4x4 f64 micro-tile. f32->f64 conversion
// happens ONCE at staging; inner loop is pure ds_read_b128 + v_fma_f64.
#define BM 64
#define BN 64
#define BK 32
#define LDM 66   // f64 row stride in doubles: 528B, 16B-aligned, pad vs 64

__global__ __launch_bounds__(256) void gemm_f64lds_kernel(
    const float* __restrict__ X,    // [B, K]
    const float* __restrict__ W,    // [N, K]
    const float* __restrict__ bias, // [N]
    float* __restrict__ dhi,        // [B, N]  (new_mem slice)
    float* __restrict__ dlo)        // [B, N]  (spike slice)
{
    __shared__ double As[BK][LDM];  // [k][m]  16.5 KB
    __shared__ double Bs[BK][LDM];  // [k][n]  16.5 KB

    const int t = threadIdx.x;
    const int row0 = blockIdx.x * BM;
    const int col0 = blockIdx.y * BN;
    const int tn = t & 15;          // 4 cols each
    const int tm = t >> 4;          // 4 rows each

    // staging map: lin 0..511 -> (r 0..63, k4 in {0,4,..,28})
    const int r0  = t >> 3;         // lin = t     -> r = t>>3
    const int k40 = (t & 7) * 4;
    const int r1  = (t + 256) >> 3;
    const int k41 = k40;            // (lin&7) identical for lin=t+256

    const float* xq0 = &X[(size_t)(row0 + r0) * K_DIM + k40];
    const float* xq1 = &X[(size_t)(row0 + r1) * K_DIM + k41];
    const float* wq0 = &W[(size_t)(col0 + r0) * K_DIM + k40];
    const float* wq1 = &W[(size_t)(col0 + r1) * K_DIM + k41];

    double acc[4][4] = {{0,0,0,0},{0,0,0,0},{0,0,0,0},{0,0,0,0}};

    // prefetch tile 0
    float4 xa0 = *(const float4*)(xq0);
    float4 xa1 = *(const float4*)(xq1);
    float4 wb0 = *(const float4*)(wq0);
    float4 wb1 = *(const float4*)(wq1);

    for (int k0 = 0; k0 < K_DIM; k0 += BK) {
        __syncthreads();            // previous tile's reads complete
        As[k40+0][r0] = (double)xa0.x; As[k40+1][r0] = (double)xa0.y;
        As[k40+2][r0] = (double)xa0.z; As[k40+3][r0] = (double)xa0.w;
        As[k41+0][r1] = (double)xa1.x; As[k41+1][r1] = (double)xa1.y;
        As[k41+2][r1] = (double)xa1.z; As[k41+3][r1] = (double)xa1.w;
        Bs[k40+0][r0] = (double)wb0.x; Bs[k40+1][r0] = (double)wb0.y;
        Bs[k40+2][r0] = (double)wb0.z; Bs[k40+3][r0] = (double)wb0.w;
        Bs[k41+0][r1] = (double)wb1.x; Bs[k41+1][r1] = (double)wb1.y;
        Bs[k41+2][r1] = (double)wb1.z; Bs[k41+3][r1] = (double)wb1.w;
        __syncthreads();

        if (k0 + BK < K_DIM) {      // prefetch next tile (hides under FMAs)
            xa0 = *(const float4*)(xq0 + k0 + BK);
            xa1 = *(const float4*)(xq1 + k0 + BK);
            wb0 = *(const float4*)(wq0 + k0 + BK);
            wb1 = *(const float4*)(wq1 + k0 + BK);
        }

        #pragma unroll
        for (int k = 0; k < BK; ++k) {
            const double2* ap = (const double2*)&As[k][tm * 4];
            const double2* bp = (const double2*)&Bs[k][tn * 4];
            double2 a01 = ap[0], a23 = ap[1];
            double2 b01 = bp[0], b23 = bp[1];
            double a0 = a01.x, a1 = a01.y, a2 = a23.x, a3 = a23.y;
            double b0 = b01.x, b1 = b01.y, b2 = b23.x, b3 = b23.y;
            acc[0][0] += a0*b0; acc[0][1] += a0*b1; acc[0][2] += a0*b2; acc[0][3] += a0*b3;
            acc[1][0] += a1*b0; acc[1][1] += a1*b1; acc[1][2] += a1*b2; acc[1][3] += a1*b3;
            acc[2][0] += a2*b0; acc[2][1] += a2*b1; acc[2][2] += a2*b2; acc[2][3] += a2*b3;
            acc[3][0] += a3*b0; acc[3][1] += a3*b1; acc[3][2] += a3*b2; acc[3][3] += a3*b3;
        }
    }

    float4 bv = *(const float4*)&bias[col0 + tn * 4];
    double bvd[4] = {(double)bv.x,(double)bv.y,(double)bv.z,(double)bv.w};
    #pragma unroll
    for (int i = 0; i < 4; ++i) {
        int row = row0 + tm * 4 + i;
        #pragma unroll
        for (int q = 0; q < 4; ++q) {
            double v = acc[i][q] + bvd[q];
            float hv = (float)v;
            float lv = (float)(v - (double)hv);
            dhi[(size_t)row * N_DIM + col0 + tn * 4 + q] = hv;
            dlo[(size_t)row * N_DIM + col0 + tn * 4 + q] = lv;
        }
    }
}

// ================= factors precompute: fac = clip(att)*0.9^delay ============
__device__ inline float pow09(int d) {
    switch (d) {
        case 0: return 1.0f;
        case 1: return 0.9f;
        case 2: return 0.81f;
        case 3: return 0.729f;
        case 4: return 0.6561f;
        case 5: return 0.59049f;
        default: return powf(0.9f, (float)d);
    }
}

__global__ __launch_bounds__(256) void factors_kernel(
    const float* __restrict__ att, const int* __restrict__ dly,
    float* __restrict__ fac)
{
    int i = blockIdx.x * 256 + threadIdx.x;    // N_DIM*BRN total
    float a = fminf(fmaxf(att[i], 0.f), 1.f);
    fac[i] = a * pow09(dly[i]);
}

// ======== fused LayerNorm + soma + axon scatter, one block per row ==========
template <int USE_FAC>
__global__ __launch_bounds__(512) void fused_row_kernel(
    const float* __restrict__ dhi, const float* __restrict__ dlo,
    const float* __restrict__ mem_i, const float* __restrict__ ref_i,
    const float* __restrict__ gamma, const float* __restrict__ beta,
    const float* __restrict__ thr_p, const float* __restrict__ dec_p,
    const float* __restrict__ att, const int* __restrict__ tgt,
    const int* __restrict__ dly, const float* __restrict__ fac,
    float* __restrict__ axon_o, float* __restrict__ spike_o,
    float* __restrict__ mem_o, float* __restrict__ ref_o)
{
    __shared__ double sm_d[N_DIM];          // 32 KB
    __shared__ float  sm_axon[NUM_TARGET];  // 16 KB
    __shared__ double red[8];

    const int b = blockIdx.x;
    const int t = threadIdx.x;
    const int lane = t & 63;
    const int wv = t >> 6;
    const float* hrow = dhi + (size_t)b * N_DIM;
    const float* lrow = dlo + (size_t)b * N_DIM;

    for (int i = t; i < NUM_TARGET; i += 512) sm_axon[i] = 0.f;

    double s = 0.0;
    #pragma unroll
    for (int j = 0; j < 2; ++j) {
        int i = t + j * 512;                 // float4 index (1024 total)
        float4 h = ((const float4*)hrow)[i];
        float4 l = ((const float4*)lrow)[i];
        double d0 = (double)h.x + (double)l.x;
        double d1 = (double)h.y + (double)l.y;
        double d2 = (double)h.z + (double)l.z;
        double d3 = (double)h.w + (double)l.w;
        sm_d[i*4+0] = d0; sm_d[i*4+1] = d1;
        sm_d[i*4+2] = d2; sm_d[i*4+3] = d3;
        s += d0 + d1 + d2 + d3;
    }
    #pragma unroll
    for (int o = 32; o > 0; o >>= 1) s += __shfl_down(s, o, 64);
    if (lane == 0) red[wv] = s;
    __syncthreads();
    const double mu = (red[0]+red[1]+red[2]+red[3]+red[4]+red[5]+red[6]+red[7])
                      * (1.0 / 4096.0);

    double vs = 0.0;
    #pragma unroll
    for (int j = 0; j < 2; ++j) {
        int i = t + j * 512;
        double d0 = sm_d[i*4+0]-mu, d1 = sm_d[i*4+1]-mu;
        double d2 = sm_d[i*4+2]-mu, d3 = sm_d[i*4+3]-mu;
        vs += d0*d0 + d1*d1 + d2*d2 + d3*d3;
    }
    #pragma unroll
    for (int o = 32; o > 0; o >>= 1) vs += __shfl_down(vs, o, 64);
    __syncthreads();                        // mu reads of red[] done
    if (lane == 0) red[wv] = vs;
    __syncthreads();
    const double var = (red[0]+red[1]+red[2]+red[3]+red[4]+red[5]+red[6]+red[7])
                       * (1.0 / 4096.0);
    const double rstd = 1.0 / sqrt(var + LN_EPS);

    for (int n = t; n < N_DIM; n += 512) {
        const int gi = b * N_DIM + n;
        double dv = (sm_d[n] - mu) * rstd * (double)gamma[n] + (double)beta[n];
        double d  = fmin(fmax((double)dec_p[n], 0.0), 1.0);
        double th = fmin(fmax((double)thr_p[n], THR_MIN), THR_MAX);
        float  rf = ref_i[gi];
        double nm = d * (double)mem_i[gi] + dv;
        bool   fired = (nm >= th) && (rf <= 0.f);
        float  sp = fired ? 1.f : 0.f;
        if (fired) nm -= th;
        float  nr = fired ? REFRACT : fmaxf(rf - 1.f, 0.f);
        float  nmf = (float)nm;
        spike_o[gi] = sp;
        mem_o[gi]   = nmf;
        ref_o[gi]   = nr;

        float sig = sp + 0.1f * (1.0f / (1.0f + expf(-nmf)));
        const int base = n * BRN;
        #pragma unroll
        for (int j = 0; j < BRN; j += 4) {
            int4 t4 = *(const int4*)&tgt[base + j];
            float f0, f1, f2, f3;
            if (USE_FAC) {
                float4 f4 = *(const float4*)&fac[base + j];
                f0 = f4.x; f1 = f4.y; f2 = f4.z; f3 = f4.w;
            } else {
                float4 a4 = *(const float4*)&att[base + j];
                int4  d4 = *(const int4*)&dly[base + j];
                f0 = fminf(fmaxf(a4.x,0.f),1.f) * pow09(d4.x);
                f1 = fminf(fmaxf(a4.y,0.f),1.f) * pow09(d4.y);
                f2 = fminf(fmaxf(a4.z,0.f),1.f) * pow09(d4.z);
                f3 = fminf(fmaxf(a4.w,0.f),1.f) * pow09(d4.w);
            }
            atomicAdd(&sm_axon[t4.x], sig * f0);
            atomicAdd(&sm_axon[t4.y], sig * f1);
            atomicAdd(&sm_axon[t4.z], sig * f2);
            atomicAdd(&sm_axon[t4.w], sig * f3);
        }
    }
    __syncthreads();

    float* arow = axon_o + (size_t)b * NUM_TARGET;
    for (int i = t; i < NUM_TARGET / 4; i += 512)
        ((float4*)arow)[i] = ((const float4*)sm_axon)[i];
}

extern "C" void kernel_launch(void* const* d_in, const int* in_sizes, int n_in,
                              void* d_out, int out_size, void* d_ws, size_t ws_size,
                              hipStream_t stream) {
    const float* x     = (const float*)d_in[0];
    const float* mem   = (const float*)d_in[1];
    const float* refr  = (const float*)d_in[2];
    const float* W     = (const float*)d_in[3];
    const float* bias  = (const float*)d_in[4];
    const float* gamma = (const float*)d_in[5];
    const float* beta  = (const float*)d_in[6];
    const float* thr   = (const float*)d_in[7];
    const float* dec   = (const float*)d_in[8];
    const float* att   = (const float*)d_in[9];
    const int*   tgt   = (const int*)d_in[10];
    const int*   dly   = (const int*)d_in[11];

    float* out   = (float*)d_out;
    const int SEC = B_DIM * N_DIM;
    float* axon  = out;
    float* spike = out + SEC;
    float* nmem  = out + 2 * SEC;
    float* nref  = out + 3 * SEC;
    float* dhi   = nmem;
    float* dlo   = spike;

    const size_t fac_bytes = (size_t)N_DIM * BRN * sizeof(float);
    const bool use_fac = ws_size >= fac_bytes;
    float* fac = (float*)d_ws;
    if (use_fac)
        factors_kernel<<<(N_DIM * BRN) / 256, 256, 0, stream>>>(att, dly, fac);

    dim3 gg(B_DIM / BM, N_DIM / BN);
    gemm_f64lds_kernel<<<gg, 256, 0, stream>>>(x, W, bias, dhi, dlo);

    if (use_fac)
        fused_row_kernel<1><<<B_DIM, 512, 0, stream>>>(
            dhi, dlo, mem, refr, gamma, beta, thr, dec, att, tgt, dly, fac,
            axon, spike, nmem, nref);
    else
        fused_row_kernel<0><<<B_DIM, 512, 0, stream>>>(
            dhi, dlo, mem, refr, gamma, beta, thr, dec, att, tgt, dly, nullptr,
            axon, spike, nmem, nref);
}

// Round 11
// 450.806 us; speedup vs baseline: 1.3669x; 1.3669x over previous
//
#include <hip/hip_runtime.h>
#include <math.h>

#define B_DIM 512
#define K_DIM 2048
#define N_DIM 4096
#define BRN 16
#define NUM_TARGET 4096

#define THR_MIN 0.5
#define THR_MAX 2.0
#define REFRACT 2.0f
#define LN_EPS 1e-5

// ===== GEMM (f64 exact, VALU): dend = X[B,K] @ W[N,K]^T + b =================
// R6-proven structure (f32 LDS [k][m], cvt in loop, conflict-free reads),
// re-tiled BM=64 x BN=32 with 4x2 micro-tile -> 1024 blocks, 4 waves/SIMD.
#define BM 64
#define BN 32
#define BK 32
#define LDA 68   // f32 row stride for As (64 + pad): reads broadcast, free
#define LDB 36   // f32 row stride for Bs (32 + pad): float2 reads cover 32 banks

__global__ __launch_bounds__(256) void gemm_f64v2_kernel(
    const float* __restrict__ X,    // [B, K]
    const float* __restrict__ W,    // [N, K]
    const float* __restrict__ bias, // [N]
    float* __restrict__ dhi,        // [B, N]  (new_mem slice)
    float* __restrict__ dlo)        // [B, N]  (spike slice)
{
    __shared__ float As[BK][LDA];   // 8.7 KB
    __shared__ float Bs[BK][LDB];   // 4.6 KB

    const int t = threadIdx.x;
    const int row0 = blockIdx.x * BM;
    const int col0 = blockIdx.y * BN;
    const int tm = t >> 4;          // 0..15 -> 4 rows each
    const int tn = t & 15;          // 0..15 -> 2 cols each

    // staging: A needs 64r x 32k = 512 float4 (2/thread); B 32r x 32k = 256 (1/thread)
    const int rA0 = t >> 3;         // 0..31
    const int kA  = (t & 7) * 4;
    const float* xq0 = &X[(size_t)(row0 + rA0) * K_DIM + kA];
    const float* xq1 = xq0 + (size_t)32 * K_DIM;
    const float* wq0 = &W[(size_t)(col0 + rA0) * K_DIM + kA];

    double acc[4][2] = {{0,0},{0,0},{0,0},{0,0}};

    float4 xa0 = *(const float4*)(xq0);
    float4 xa1 = *(const float4*)(xq1);
    float4 wb0 = *(const float4*)(wq0);

    for (int k0 = 0; k0 < K_DIM; k0 += BK) {
        __syncthreads();            // previous tile's reads complete
        As[kA+0][rA0]      = xa0.x; As[kA+1][rA0]      = xa0.y;
        As[kA+2][rA0]      = xa0.z; As[kA+3][rA0]      = xa0.w;
        As[kA+0][rA0 + 32] = xa1.x; As[kA+1][rA0 + 32] = xa1.y;
        As[kA+2][rA0 + 32] = xa1.z; As[kA+3][rA0 + 32] = xa1.w;
        Bs[kA+0][rA0]      = wb0.x; Bs[kA+1][rA0]      = wb0.y;
        Bs[kA+2][rA0]      = wb0.z; Bs[kA+3][rA0]      = wb0.w;
        __syncthreads();

        if (k0 + BK < K_DIM) {      // prefetch next tile (hides under FMAs)
            xa0 = *(const float4*)(xq0 + k0 + BK);
            xa1 = *(const float4*)(xq1 + k0 + BK);
            wb0 = *(const float4*)(wq0 + k0 + BK);
        }

        #pragma unroll
        for (int k = 0; k < BK; ++k) {
            float4 a = *(const float4*)&As[k][tm * 4];
            float2 bq = *(const float2*)&Bs[k][tn * 2];
            double a0 = (double)a.x, a1 = (double)a.y;
            double a2 = (double)a.z, a3 = (double)a.w;
            double b0 = (double)bq.x, b1 = (double)bq.y;
            acc[0][0] += a0*b0; acc[0][1] += a0*b1;
            acc[1][0] += a1*b0; acc[1][1] += a1*b1;
            acc[2][0] += a2*b0; acc[2][1] += a2*b1;
            acc[3][0] += a3*b0; acc[3][1] += a3*b1;
        }
    }

    float2 bv = *(const float2*)&bias[col0 + tn * 2];
    const double bd0 = (double)bv.x, bd1 = (double)bv.y;
    #pragma unroll
    for (int i = 0; i < 4; ++i) {
        const int row = row0 + tm * 4 + i;
        double v0 = acc[i][0] + bd0;
        double v1 = acc[i][1] + bd1;
        float2 hv, lv;
        hv.x = (float)v0; lv.x = (float)(v0 - (double)hv.x);
        hv.y = (float)v1; lv.y = (float)(v1 - (double)hv.y);
        *(float2*)&dhi[(size_t)row * N_DIM + col0 + tn * 2] = hv;
        *(float2*)&dlo[(size_t)row * N_DIM + col0 + tn * 2] = lv;
    }
}

// ================= factors precompute: fac = clip(att)*0.9^delay ============
__device__ inline float pow09(int d) {
    switch (d) {
        case 0: return 1.0f;
        case 1: return 0.9f;
        case 2: return 0.81f;
        case 3: return 0.729f;
        case 4: return 0.6561f;
        case 5: return 0.59049f;
        default: return powf(0.9f, (float)d);
    }
}

__global__ __launch_bounds__(256) void factors_kernel(
    const float* __restrict__ att, const int* __restrict__ dly,
    float* __restrict__ fac)
{
    int i = blockIdx.x * 256 + threadIdx.x;    // N_DIM*BRN total
    float a = fminf(fmaxf(att[i], 0.f), 1.f);
    fac[i] = a * pow09(dly[i]);
}

// ======== fused LayerNorm + soma + axon scatter =============================
// 1024 threads/block (16 waves -> 8 waves/SIMD at 2 blocks/CU), dend held in
// registers (4 neurons/thread), LDS = axon accumulator + reduction slots only.
template <int USE_FAC>
__global__ __launch_bounds__(1024) void fused_row_kernel(
    const float* __restrict__ dhi, const float* __restrict__ dlo,
    const float* __restrict__ mem_i, const float* __restrict__ ref_i,
    const float* __restrict__ gamma, const float* __restrict__ beta,
    const float* __restrict__ thr_p, const float* __restrict__ dec_p,
    const float* __restrict__ att, const int* __restrict__ tgt,
    const int* __restrict__ dly, const float* __restrict__ fac,
    float* __restrict__ axon_o, float* __restrict__ spike_o,
    float* __restrict__ mem_o, float* __restrict__ ref_o)
{
    __shared__ float  sm_axon[NUM_TARGET];  // 16 KB
    __shared__ double red[16];
    __shared__ double red2[16];

    const int b = blockIdx.x;
    const int t = threadIdx.x;
    const int lane = t & 63;
    const int wv = t >> 6;                  // 0..15

    // zero axon accumulator (4096 floats / 1024 thr = 1 float4)
    ((float4*)sm_axon)[t] = make_float4(0.f, 0.f, 0.f, 0.f);

    // load this thread's 4 neurons of exact f64 dend
    const float4 h = ((const float4*)(dhi + (size_t)b * N_DIM))[t];
    const float4 l = ((const float4*)(dlo + (size_t)b * N_DIM))[t];
    double d0 = (double)h.x + (double)l.x;
    double d1 = (double)h.y + (double)l.y;
    double d2 = (double)h.z + (double)l.z;
    double d3 = (double)h.w + (double)l.w;

    double s = d0 + d1 + d2 + d3;
    #pragma unroll
    for (int o = 32; o > 0; o >>= 1) s += __shfl_down(s, o, 64);
    if (lane == 0) red[wv] = s;
    __syncthreads();
    double mu = 0.0;
    #pragma unroll
    for (int i = 0; i < 16; ++i) mu += red[i];
    mu *= (1.0 / 4096.0);

    double e0 = d0 - mu, e1 = d1 - mu, e2 = d2 - mu, e3 = d3 - mu;
    double vs = e0*e0 + e1*e1 + e2*e2 + e3*e3;
    #pragma unroll
    for (int o = 32; o > 0; o >>= 1) vs += __shfl_down(vs, o, 64);
    if (lane == 0) red2[wv] = vs;
    __syncthreads();
    double var = 0.0;
    #pragma unroll
    for (int i = 0; i < 16; ++i) var += red2[i];
    var *= (1.0 / 4096.0);
    const double rstd = 1.0 / sqrt(var + LN_EPS);

    // soma for 4 consecutive neurons n0 = t*4
    const float4 g4 = ((const float4*)gamma)[t];
    const float4 be4 = ((const float4*)beta)[t];
    const float4 th4 = ((const float4*)thr_p)[t];
    const float4 dc4 = ((const float4*)dec_p)[t];
    const float4 mi4 = ((const float4*)(mem_i + (size_t)b * N_DIM))[t];
    const float4 ri4 = ((const float4*)(ref_i + (size_t)b * N_DIM))[t];

    float4 sp4, nm4, nr4, sg4;
    {
        const double dd[4] = {d0, d1, d2, d3};
        const float gg[4] = {g4.x, g4.y, g4.z, g4.w};
        const float bb[4] = {be4.x, be4.y, be4.z, be4.w};
        const float tt[4] = {th4.x, th4.y, th4.z, th4.w};
        const float cc[4] = {dc4.x, dc4.y, dc4.z, dc4.w};
        const float mm[4] = {mi4.x, mi4.y, mi4.z, mi4.w};
        const float rr[4] = {ri4.x, ri4.y, ri4.z, ri4.w};
        float spv[4], nmv[4], nrv[4], sgv[4];
        #pragma unroll
        for (int q = 0; q < 4; ++q) {
            double dv = (dd[q] - mu) * rstd * (double)gg[q] + (double)bb[q];
            double dcl = fmin(fmax((double)cc[q], 0.0), 1.0);
            double th = fmin(fmax((double)tt[q], THR_MIN), THR_MAX);
            float  rf = rr[q];
            double nm = dcl * (double)mm[q] + dv;
            bool   fired = (nm >= th) && (rf <= 0.f);
            if (fired) nm -= th;
            float nmf = (float)nm;
            spv[q] = fired ? 1.f : 0.f;
            nmv[q] = nmf;
            nrv[q] = fired ? REFRACT : fmaxf(rf - 1.f, 0.f);
            sgv[q] = spv[q] + 0.1f * (1.0f / (1.0f + expf(-nmf)));
        }
        sp4 = make_float4(spv[0], spv[1], spv[2], spv[3]);
        nm4 = make_float4(nmv[0], nmv[1], nmv[2], nmv[3]);
        nr4 = make_float4(nrv[0], nrv[1], nrv[2], nrv[3]);
        sg4 = make_float4(sgv[0], sgv[1], sgv[2], sgv[3]);
    }
    ((float4*)(spike_o + (size_t)b * N_DIM))[t] = sp4;
    ((float4*)(mem_o   + (size_t)b * N_DIM))[t] = nm4;
    ((float4*)(ref_o   + (size_t)b * N_DIM))[t] = nr4;

    // scatter: 4 neurons x 16 branches
    const float sgv[4] = {sg4.x, sg4.y, sg4.z, sg4.w};
    #pragma unroll
    for (int q = 0; q < 4; ++q) {
        const float sig = sgv[q];
        const int base = (t * 4 + q) * BRN;
        #pragma unroll
        for (int j = 0; j < BRN; j += 4) {
            int4 t4 = *(const int4*)&tgt[base + j];
            float f0, f1, f2, f3;
            if (USE_FAC) {
                float4 f4 = *(const float4*)&fac[base + j];
                f0 = f4.x; f1 = f4.y; f2 = f4.z; f3 = f4.w;
            } else {
                float4 a4 = *(const float4*)&att[base + j];
                int4  d4 = *(const int4*)&dly[base + j];
                f0 = fminf(fmaxf(a4.x,0.f),1.f) * pow09(d4.x);
                f1 = fminf(fmaxf(a4.y,0.f),1.f) * pow09(d4.y);
                f2 = fminf(fmaxf(a4.z,0.f),1.f) * pow09(d4.z);
                f3 = fminf(fmaxf(a4.w,0.f),1.f) * pow09(d4.w);
            }
            atomicAdd(&sm_axon[t4.x], sig * f0);
            atomicAdd(&sm_axon[t4.y], sig * f1);
            atomicAdd(&sm_axon[t4.z], sig * f2);
            atomicAdd(&sm_axon[t4.w], sig * f3);
        }
    }
    __syncthreads();

    ((float4*)(axon_o + (size_t)b * NUM_TARGET))[t] = ((const float4*)sm_axon)[t];
}

extern "C" void kernel_launch(void* const* d_in, const int* in_sizes, int n_in,
                              void* d_out, int out_size, void* d_ws, size_t ws_size,
                              hipStream_t stream) {
    const float* x     = (const float*)d_in[0];
    const float* mem   = (const float*)d_in[1];
    const float* refr  = (const float*)d_in[2];
    const float* W     = (const float*)d_in[3];
    const float* bias  = (const float*)d_in[4];
    const float* gamma = (const float*)d_in[5];
    const float* beta  = (const float*)d_in[6];
    const float* thr   = (const float*)d_in[7];
    const float* dec   = (const float*)d_in[8];
    const float* att   = (const float*)d_in[9];
    const int*   tgt   = (const int*)d_in[10];
    const int*   dly   = (const int*)d_in[11];

    float* out   = (float*)d_out;
    const int SEC = B_DIM * N_DIM;
    float* axon  = out;
    float* spike = out + SEC;
    float* nmem  = out + 2 * SEC;
    float* nref  = out + 3 * SEC;
    float* dhi   = nmem;
    float* dlo   = spike;

    const size_t fac_bytes = (size_t)N_DIM * BRN * sizeof(float);
    const bool use_fac = ws_size >= fac_bytes;
    float* fac = (float*)d_ws;
    if (use_fac)
        factors_kernel<<<(N_DIM * BRN) / 256, 256, 0, stream>>>(att, dly, fac);

    dim3 gg(B_DIM / BM, N_DIM / BN);   // 8 x 128 = 1024 blocks
    gemm_f64v2_kernel<<<gg, 256, 0, stream>>>(x, W, bias, dhi, dlo);

    if (use_fac)
        fused_row_kernel<1><<<B_DIM, 1024, 0, stream>>>(
            dhi, dlo, mem, refr, gamma, beta, thr, dec, att, tgt, dly, fac,
            axon, spike, nmem, nref);
    else
        fused_row_kernel<0><<<B_DIM, 1024, 0, stream>>>(
            dhi, dlo, mem, refr, gamma, beta, thr, dec, att, tgt, dly, nullptr,
            axon, spike, nmem, nref);
}